// Round 10
// baseline (396.035 us; speedup 1.0000x reference)
//
#include <hip/hip_runtime.h>

// Gemma4 vision average pooling: [B,N,H] -> [B,OUT_LEN,H]
// MEASUREMENT PROBE ROUND: the single-pass kernel (round 3: passed, absmax 0,
// dur_us 395.7) is invisible in rocprof top-5 (crowded out by 182 µs harness
// ws-poison fills), so kernel-only time K is unknown (dur_us includes ~275 µs
// of harness reset work). This kernel repeats the identical pass 4x inside one
// dispatch:
//   - dispatch dur ~= 4K > 182 µs -> tops the profile -> direct BW counters
//   - dur_us_new ~= floor + 4K; round3 = floor + K  =>  K = (new - 395.7)/3
//   - FETCH_SIZE cross-check: ideal ~1.18e6 KB (4 x 295 MB); if much lower,
//     L3 absorbed re-reads and the dur-based K skews low.
// Each pass writes identical output; a memory clobber between passes prevents
// load CSE across the __restrict__ pointers (keeps all 4 passes' HBM traffic).

#define BATCH   16
#define NPATCH  4096
#define HID     1152
#define HV      288      // HID / 4 (float4 units)
#define GRIDW   64
#define PK      4
#define OUTW    16       // GRIDW / PK
#define OUTLEN  256      // OUTW * OUTW
#define REPEAT  4

__global__ __launch_bounds__(256) void
gemma4_pool_probe4_kernel(const float4* __restrict__ in, float4* __restrict__ out) {
    int idx = blockIdx.x * blockDim.x + threadIdx.x;  // grid sized exactly
    int hv = idx % HV;          // float4 column within hidden dim
    int bo = idx / HV;          // (b, o) flat
    int o  = bo & (OUTLEN - 1);
    int b  = bo >> 8;
    int ox = o & (OUTW - 1);
    int oy = o >> 4;

    // first contributing patch row: p0 = oy*4*64 + ox*4
    const float4* base = in + ((size_t)b * NPATCH + (size_t)(oy * (PK * GRIDW) + ox * PK)) * HV + hv;
    const float scale = 2.1213203435596424f;  // sqrt(1152) / 16

    for (int r = 0; r < REPEAT; ++r) {
        float4 s = make_float4(0.f, 0.f, 0.f, 0.f);
#pragma unroll
        for (int dy = 0; dy < PK; ++dy) {
#pragma unroll
            for (int dx = 0; dx < PK; ++dx) {
                float4 v = base[(size_t)(dy * GRIDW + dx) * HV];
                s.x += v.x; s.y += v.y; s.z += v.z; s.w += v.w;
            }
        }
        float4 t;
        t.x = s.x * scale; t.y = s.y * scale; t.z = s.z * scale; t.w = s.w * scale;
        out[idx] = t;
        // Force each pass's loads/stores to actually issue (no CSE across passes).
        asm volatile("" ::: "memory");
    }
}

extern "C" void kernel_launch(void* const* d_in, const int* in_sizes, int n_in,
                              void* d_out, int out_size, void* d_ws, size_t ws_size,
                              hipStream_t stream) {
    const float4* in  = (const float4*)d_in[0];   // [B, N, H] fp32
    float4*       out = (float4*)d_out;           // [B, OUTLEN, H] fp32

    const int total_v4 = BATCH * OUTLEN * HV;     // 1,179,648
    const int block = 256;
    const int grid  = total_v4 / block;           // 4608, exact

    gemma4_pool_probe4_kernel<<<grid, block, 0, stream>>>(in, out);
}